// Round 6
// baseline (658.381 us; speedup 1.0000x reference)
//
#include <hip/hip_runtime.h>
#include <hip/hip_bf16.h>
#include <math.h>

// Problem constants
#define BB 16
#define NN 4096
#define CC 256
#define NC 768     // 3*C
#define MTOT (BB * NN)   // 65536 tokens

typedef __attribute__((ext_vector_type(8))) __bf16 bf16x8;
typedef __attribute__((ext_vector_type(4))) float f32x4;

__device__ __forceinline__ unsigned short f2bf(float f) {
    union { float f; unsigned int u; } v; v.f = f;
    unsigned int r = (v.u + 0x7FFFu + ((v.u >> 16) & 1u)) >> 16;
    return (unsigned short)r;
}
__device__ __forceinline__ float bf2f(unsigned short b) {
    union { unsigned int u; float f; } v; v.u = ((unsigned int)b) << 16;
    return v.f;
}

#define GL16(gp, lp) \
    __builtin_amdgcn_global_load_lds((const __attribute__((address_space(1))) void*)(gp), \
                                     (__attribute__((address_space(3))) void*)(lp), 16, 0, 0)

// ---------------------------------------------------------------------------
// m97-style GEMM core for the tiny weight-prep GEMMs (K=256).
// ---------------------------------------------------------------------------
template<int KDIM>
__device__ __forceinline__ void gemm_tile(const unsigned short* __restrict__ A,
                                          const unsigned short* __restrict__ Bt,
                                          int bm, int bn,
                                          unsigned short* As, unsigned short* Bs,
                                          f32x4 (&acc)[4][4]) {
    const int tid = threadIdx.x;
    const int lane = tid & 63;
    const int wave = tid >> 6;
    const int q = lane >> 4;
    const int r16 = lane & 15;
    const int wm = (wave >> 1) * 64;
    const int wn = (wave & 1) * 64;

    const int e0 = tid, e1 = tid + 256;
    const int r0 = e0 >> 2, r1 = e1 >> 2;
    const int kc0 = (e0 & 3) ^ ((r0 >> 1) & 3);
    const int kc1 = (e1 & 3) ^ ((r1 >> 1) & 3);
    const unsigned short* gA0 = A + (size_t)(bm + r0) * KDIM + kc0 * 8;
    const unsigned short* gA1 = A + (size_t)(bm + r1) * KDIM + kc1 * 8;
    const unsigned short* gB0 = Bt + (size_t)(bn + r0) * KDIM + kc0 * 8;
    const unsigned short* gB1 = Bt + (size_t)(bn + r1) * KDIM + kc1 * 8;

    const int sw = (q ^ ((r16 >> 1) & 3)) * 8;

    for (int kt = 0; kt < KDIM; kt += 32) {
        if (kt) __syncthreads();
        GL16(gA0 + kt, As + e0 * 8);
        GL16(gA1 + kt, As + e1 * 8);
        GL16(gB0 + kt, Bs + e0 * 8);
        GL16(gB1 + kt, Bs + e1 * 8);
        __syncthreads();

        bf16x8 af[4], bfr[4];
#pragma unroll
        for (int mi = 0; mi < 4; ++mi)
            af[mi] = *(const bf16x8*)(As + (wm + mi * 16 + r16) * 32 + sw);
#pragma unroll
        for (int ni = 0; ni < 4; ++ni)
            bfr[ni] = *(const bf16x8*)(Bs + (wn + ni * 16 + r16) * 32 + sw);
#pragma unroll
        for (int mi = 0; mi < 4; ++mi)
#pragma unroll
            for (int ni = 0; ni < 4; ++ni)
                acc[mi][ni] = __builtin_amdgcn_mfma_f32_16x16x32_bf16(
                    af[mi], bfr[ni], acc[mi][ni], 0, 0, 0);
    }
}

// ---------------------------------------------------------------------------
// Fused converter: Wqkv -> Wqb/Wkb/Wvs (bf16), Wproj -> WpT (bf16 transposed)
// ---------------------------------------------------------------------------
__global__ __launch_bounds__(256) void conv_all(const float* __restrict__ Wqkv,
                                                const float* __restrict__ Wproj,
                                                unsigned short* __restrict__ Wqb,
                                                unsigned short* __restrict__ Wkb,
                                                unsigned short* __restrict__ Wvs,
                                                unsigned short* __restrict__ WpT) {
    int t = blockIdx.x * 256 + threadIdx.x;
    if (t < 3 * CC * NC) {
        unsigned short v = f2bf(Wqkv[t]);
        int ic = t / NC;           // i*256 + a  (input channel a)
        int col = t - ic * NC;
        if (col < 256)       Wqb[(size_t)ic * CC + col] = v;
        else if (col < 512)  Wkb[(size_t)ic * CC + col - 256] = v;
        else                 Wvs[(size_t)ic * CC + col - 512] = v;
    } else {
        int e = t - 3 * CC * NC;   // < 65536
        int g = e >> 8, c = e & 255;
        WpT[e] = f2bf(Wproj[(size_t)c * CC + g]);   // WpT[g][c] = Wproj[c][g]
    }
}

// ---------------------------------------------------------------------------
// Batched weight GEMM: z<3 -> MtY_i = scale * Wk_i Wq_i^T  (256x256)
//                      z=3 -> PtZ = (1/3) * Wproj^T x Wv   (256x768)
// ---------------------------------------------------------------------------
__global__ __launch_bounds__(256) void wgemm(const unsigned short* __restrict__ Wqb,
                                             const unsigned short* __restrict__ Wkb,
                                             const unsigned short* __restrict__ Wvs,
                                             const unsigned short* __restrict__ WpT,
                                             unsigned short* __restrict__ MtY,
                                             unsigned short* __restrict__ PtZ) {
    const int z = blockIdx.z;
    const unsigned short *A, *Bt;
    unsigned short* C;
    int nout; float mult;
    if (z < 3) {
        if (blockIdx.x >= 2) return;
        A = Wkb + z * CC * CC; Bt = Wqb + z * CC * CC; C = MtY + z * CC * CC;
        nout = CC; mult = 0.0625f;            // C^-0.5
    } else {
        A = WpT; Bt = Wvs; C = PtZ;
        nout = NC; mult = 1.0f / 3.0f;
    }

    __shared__ unsigned short As[128 * 32];
    __shared__ unsigned short Bs[128 * 32];
    f32x4 acc[4][4];
#pragma unroll
    for (int i = 0; i < 4; ++i)
#pragma unroll
        for (int j = 0; j < 4; ++j) acc[i][j] = {0.f, 0.f, 0.f, 0.f};

    gemm_tile<CC>(A, Bt, blockIdx.y * 128, blockIdx.x * 128, As, Bs, acc);

    const int lane = threadIdx.x & 63;
    const int wave = threadIdx.x >> 6;
    const int q = lane >> 4, r16 = lane & 15;
    const int wm = (wave >> 1) * 64, wn = (wave & 1) * 64;
#pragma unroll
    for (int mi = 0; mi < 4; ++mi)
#pragma unroll
        for (int ni = 0; ni < 4; ++ni) {
            int row0 = blockIdx.y * 128 + wm + mi * 16 + q * 4;
            int col = blockIdx.x * 128 + wn + ni * 16 + r16;
#pragma unroll
            for (int r = 0; r < 4; ++r)
                C[(size_t)(row0 + r) * nout + col] = f2bf(acc[mi][ni][r] * mult);
        }
}

// ---------------------------------------------------------------------------
// MEGA kernel, skewed-pipeline version.
// Per block of 64 tokens, per dilation i:
//   P1: Y_i = x @ M_i^T (MFMA -> ybuf), weights double-buffer staged, ONE
//       barrier per stage (loads drained by the *next* barrier = full overlap)
//   P2: attention (y from LDS, x windows fp32 from global), z -> ybuf
//   P3: oacc += z @ P_i  (same pipeline)
// Cross-phase prefetch keeps the weight stream always one slice ahead.
// LDS: ybuf 33792 + bstage 2x8192 + part 3072 = 53248 B -> 3 blocks/CU.
// ---------------------------------------------------------------------------
__global__ __launch_bounds__(256, 3) void mega(const float* __restrict__ xf,
                                               const unsigned short* __restrict__ MtY,
                                               const unsigned short* __restrict__ PtZ,
                                               const float* __restrict__ bias,
                                               float* __restrict__ out) {
    __shared__ __align__(16) unsigned short ybuf[64 * 264];
    __shared__ __align__(16) unsigned short bstage[2][4096];
    __shared__ __align__(16) float part[768];

    const int tid = threadIdx.x;
    const int lane = tid & 63;
    const int wave = tid >> 6;
    const int q = lane >> 4;
    const int r16 = lane & 15;
    const int t0 = blockIdx.x * 64;

    // Stage one 128-col x 32-k weight slice (8 KB) into bstage[b].
    // Slot e holds cols (e>>2), k-chunk swizzled by ((col>>1)&3) for
    // conflict-free b128 fragment reads (<=2-way, free per m136).
    auto stage_M = [&](int ii, int s, int b) {
        int nh = s >> 3, kt = s & 7;
#pragma unroll
        for (int h = 0; h < 2; ++h) {
            int e = tid + h * 256;
            int col = e >> 2;
            int kc = (e & 3) ^ ((col >> 1) & 3);
            GL16(MtY + (size_t)(ii * 256 + nh * 128 + col) * CC + kt * 32 + kc * 8,
                 bstage[b] + e * 8);
        }
    };
    auto stage_P = [&](int ii, int s, int b) {
        int nh = s >> 3, kt = s & 7;
#pragma unroll
        for (int h = 0; h < 2; ++h) {
            int e = tid + h * 256;
            int col = e >> 2;
            int kc = (e & 3) ^ ((col >> 1) & 3);
            GL16(PtZ + (size_t)(nh * 128 + col) * NC + ii * 256 + kt * 32 + kc * 8,
                 bstage[b] + e * 8);
        }
    };

    // Persistent A-fragments: wave's 16 tokens, fp32 x -> bf16, once.
    const float* xrow = xf + (size_t)(t0 + wave * 16 + r16) * CC;
    bf16x8 af[8];
#pragma unroll
    for (int kt = 0; kt < 8; ++kt) {
        float4 a = *(const float4*)(xrow + kt * 32 + q * 8);
        float4 b = *(const float4*)(xrow + kt * 32 + q * 8 + 4);
        unsigned short p[8];
        p[0] = f2bf(a.x); p[1] = f2bf(a.y); p[2] = f2bf(a.z); p[3] = f2bf(a.w);
        p[4] = f2bf(b.x); p[5] = f2bf(b.y); p[6] = f2bf(b.z); p[7] = f2bf(b.w);
        af[kt] = *(const bf16x8*)p;
    }

    f32x4 oacc[16];
#pragma unroll
    for (int j = 0; j < 16; ++j) oacc[j] = {0.f, 0.f, 0.f, 0.f};

    stage_M(0, 0, 0);    // very first slice

    for (int i = 0; i < 3; ++i) {
        // ================= Phase 1: Y = x @ M_i^T =================
        f32x4 yacc[8];
        for (int s = 0; s < 16; ++s) {
            const int nh = s >> 3, kt = s & 7;
            if (kt == 0) {
#pragma unroll
                for (int j = 0; j < 8; ++j) yacc[j] = {0.f, 0.f, 0.f, 0.f};
            }
            __syncthreads();                 // drains stage(s); frees buf[(s+1)&1]
            if (s < 15) stage_M(i, s + 1, (s + 1) & 1);
            else        stage_P(i, 0, 0);    // prefetch phase-3 first slice

            const unsigned short* bp = bstage[s & 1];
#pragma unroll
            for (int nf = 0; nf < 8; ++nf) {
                int col = nf * 16 + r16;
                int ch = q ^ ((col >> 1) & 3);
                bf16x8 b = *(const bf16x8*)(bp + (col * 4 + ch) * 8);
                yacc[nf] = __builtin_amdgcn_mfma_f32_16x16x32_bf16(
                    af[kt], b, yacc[nf], 0, 0, 0);
            }
            if (kt == 7) {
#pragma unroll
                for (int nf = 0; nf < 8; ++nf)
#pragma unroll
                    for (int r = 0; r < 4; ++r)
                        ybuf[(wave * 16 + q * 4 + r) * 264 + nh * 128 + nf * 16 + r16] =
                            f2bf(yacc[nf][r]);
            }
        }
        __syncthreads();   // y ready

        // ================= Phase 2: attention =================
        {
            const int t = lane, seg = wave;
            const int d = i + 1;
            const int ns = (t0 + t) & (NN - 1);
            const bool vlo = ns >= d;
            const bool vhi = ns + d < NN;
            const float* x1 = xf + (size_t)(t0 + t) * CC + seg * 64;
            const float* x0 = vlo ? x1 - (size_t)d * CC : x1;
            const float* x2 = vhi ? x1 + (size_t)d * CC : x1;
            const unsigned short* yr = ybuf + t * 264 + seg * 64;

            float p0 = 0.f, p1 = 0.f, p2 = 0.f;
#pragma unroll
            for (int kk = 0; kk < 16; ++kk) {
                ushort4 yu = *(const ushort4*)(yr + kk * 4);
                float y0 = bf2f(yu.x), y1 = bf2f(yu.y), y2 = bf2f(yu.z), y3 = bf2f(yu.w);
                float4 a = *(const float4*)(x0 + kk * 4);
                float4 b = *(const float4*)(x1 + kk * 4);
                float4 c = *(const float4*)(x2 + kk * 4);
                p0 += y0 * a.x + y1 * a.y + y2 * a.z + y3 * a.w;
                p1 += y0 * b.x + y1 * b.y + y2 * b.z + y3 * b.w;
                p2 += y0 * c.x + y1 * c.y + y2 * c.z + y3 * c.w;
            }
            int pb = (seg * 64 + t) * 3;
            part[pb] = p0; part[pb + 1] = p1; part[pb + 2] = p2;
            __syncthreads();

            float l0 = 0.f, l1 = 0.f, l2 = 0.f;
#pragma unroll
            for (int s4 = 0; s4 < 4; ++s4) {
                int b = (s4 * 64 + t) * 3;
                l0 += part[b]; l1 += part[b + 1]; l2 += part[b + 2];
            }
            if (!vlo) l0 = 0.f;        // zero-logit padding (matches reference)
            if (!vhi) l2 = 0.f;
            float mx = fmaxf(l0, fmaxf(l1, l2));
            float e0 = __expf(l0 - mx), e1 = __expf(l1 - mx), e2 = __expf(l2 - mx);
            float inv = 1.0f / (e0 + e1 + e2);
            float w0 = vlo ? e0 * inv : 0.f;
            float w1 = e1 * inv;
            float w2 = vhi ? e2 * inv : 0.f;

            unsigned short* zr = ybuf + t * 264 + seg * 64;
#pragma unroll
            for (int kk = 0; kk < 8; ++kk) {
                float4 a = *(const float4*)(x0 + kk * 8);
                float4 a2 = *(const float4*)(x0 + kk * 8 + 4);
                float4 b = *(const float4*)(x1 + kk * 8);
                float4 b2 = *(const float4*)(x1 + kk * 8 + 4);
                float4 c = *(const float4*)(x2 + kk * 8);
                float4 c2 = *(const float4*)(x2 + kk * 8 + 4);
                unsigned short zs[8];
                zs[0] = f2bf(w0 * a.x + w1 * b.x + w2 * c.x);
                zs[1] = f2bf(w0 * a.y + w1 * b.y + w2 * c.y);
                zs[2] = f2bf(w0 * a.z + w1 * b.z + w2 * c.z);
                zs[3] = f2bf(w0 * a.w + w1 * b.w + w2 * c.w);
                zs[4] = f2bf(w0 * a2.x + w1 * b2.x + w2 * c2.x);
                zs[5] = f2bf(w0 * a2.y + w1 * b2.y + w2 * c2.y);
                zs[6] = f2bf(w0 * a2.z + w1 * b2.z + w2 * c2.z);
                zs[7] = f2bf(w0 * a2.w + w1 * b2.w + w2 * c2.w);
                *(float4*)(zr + kk * 8) = *(const float4*)zs;
            }
        }

        // ================= Phase 3: oacc += z @ P_i =================
        for (int s = 0; s < 16; ++s) {
            const int nh = s >> 3, kt = s & 7;
            __syncthreads();                 // drains stage(s); z visible at s=0
            if (s < 15)      stage_P(i, s + 1, (s + 1) & 1);
            else if (i < 2)  stage_M(i + 1, 0, 0);   // prefetch next dilation

            bf16x8 a = *(const bf16x8*)(ybuf + (wave * 16 + r16) * 264 +
                                        kt * 32 + q * 8);
            const unsigned short* bp = bstage[s & 1];
#pragma unroll
            for (int nf = 0; nf < 8; ++nf) {
                int col = nf * 16 + r16;
                int ch = q ^ ((col >> 1) & 3);
                bf16x8 b = *(const bf16x8*)(bp + (col * 4 + ch) * 8);
                oacc[nh * 8 + nf] = __builtin_amdgcn_mfma_f32_16x16x32_bf16(
                    a, b, oacc[nh * 8 + nf], 0, 0, 0);
            }
        }
    }

    // ================= Epilogue =================
#pragma unroll
    for (int nh = 0; nh < 2; ++nh)
#pragma unroll
        for (int nf = 0; nf < 8; ++nf) {
            int g = nh * 128 + nf * 16 + r16;
            float bc = bias[g];
            f32x4 v = oacc[nh * 8 + nf];
#pragma unroll
            for (int r = 0; r < 4; ++r)
                out[(size_t)(t0 + wave * 16 + q * 4 + r) * CC + g] = v[r] + bc;
        }
}

// ---------------------------------------------------------------------------
extern "C" void kernel_launch(void* const* d_in, const int* in_sizes, int n_in,
                              void* d_out, int out_size, void* d_ws, size_t ws_size,
                              hipStream_t stream) {
    const float* x = (const float*)d_in[0];      // (16, 4096, 256)
    const float* Wqkv = (const float*)d_in[1];   // (3, 256, 768)
    const float* Wproj = (const float*)d_in[2];  // (256, 256)
    const float* bproj = (const float*)d_in[3];  // (256,)
    float* out = (float*)d_out;                  // (16, 4096, 256)

    unsigned short* Wqb = (unsigned short*)d_ws;           // 3*256*256
    unsigned short* Wkb = Wqb + (size_t)3 * CC * CC;
    unsigned short* Wvs = Wkb + (size_t)3 * CC * CC;       // (768,256): [(i,a)][c]
    unsigned short* WpT = Wvs + (size_t)3 * CC * CC;       // (256,256): [g][c]
    unsigned short* MtY = WpT + (size_t)CC * CC;           // (768,256): [(i,b)][a]
    unsigned short* PtZ = MtY + (size_t)NC * CC;           // (256,768): [g][(i,a)]

    conv_all<<<(3 * CC * NC + CC * CC) / 256, 256, 0, stream>>>(
        Wqkv, Wproj, Wqb, Wkb, Wvs, WpT);
    wgemm<<<dim3(6, 2, 4), 256, 0, stream>>>(Wqb, Wkb, Wvs, WpT, MtY, PtZ);
    mega<<<MTOT / 64, 256, 0, stream>>>(x, MtY, PtZ, bproj, out);
}

// Round 7
// 252.066 us; speedup vs baseline: 2.6119x; 2.6119x over previous
//
#include <hip/hip_runtime.h>
#include <hip/hip_bf16.h>
#include <math.h>

// Problem constants
#define BB 16
#define NN 4096
#define CC 256
#define NC 768     // 3*C
#define MTOT (BB * NN)   // 65536 tokens

typedef __attribute__((ext_vector_type(8))) __bf16 bf16x8;
typedef __attribute__((ext_vector_type(4))) float f32x4;

__device__ __forceinline__ unsigned short f2bf(float f) {
    union { float f; unsigned int u; } v; v.f = f;
    unsigned int r = (v.u + 0x7FFFu + ((v.u >> 16) & 1u)) >> 16;
    return (unsigned short)r;
}
__device__ __forceinline__ float bf2f(unsigned short b) {
    union { unsigned int u; float f; } v; v.u = ((unsigned int)b) << 16;
    return v.f;
}

#define GL16(gp, lp) \
    __builtin_amdgcn_global_load_lds((const __attribute__((address_space(1))) void*)(gp), \
                                     (__attribute__((address_space(3))) void*)(lp), 16, 0, 0)

// ---------------------------------------------------------------------------
// m97-style GEMM core for the tiny weight-prep GEMMs (K=256).
// ---------------------------------------------------------------------------
template<int KDIM>
__device__ __forceinline__ void gemm_tile(const unsigned short* __restrict__ A,
                                          const unsigned short* __restrict__ Bt,
                                          int bm, int bn,
                                          unsigned short* As, unsigned short* Bs,
                                          f32x4 (&acc)[4][4]) {
    const int tid = threadIdx.x;
    const int lane = tid & 63;
    const int wave = tid >> 6;
    const int q = lane >> 4;
    const int r16 = lane & 15;
    const int wm = (wave >> 1) * 64;
    const int wn = (wave & 1) * 64;

    const int e0 = tid, e1 = tid + 256;
    const int r0 = e0 >> 2, r1 = e1 >> 2;
    const int kc0 = (e0 & 3) ^ ((r0 >> 1) & 3);
    const int kc1 = (e1 & 3) ^ ((r1 >> 1) & 3);
    const unsigned short* gA0 = A + (size_t)(bm + r0) * KDIM + kc0 * 8;
    const unsigned short* gA1 = A + (size_t)(bm + r1) * KDIM + kc1 * 8;
    const unsigned short* gB0 = Bt + (size_t)(bn + r0) * KDIM + kc0 * 8;
    const unsigned short* gB1 = Bt + (size_t)(bn + r1) * KDIM + kc1 * 8;

    const int sw = (q ^ ((r16 >> 1) & 3)) * 8;

    for (int kt = 0; kt < KDIM; kt += 32) {
        if (kt) __syncthreads();
        GL16(gA0 + kt, As + e0 * 8);
        GL16(gA1 + kt, As + e1 * 8);
        GL16(gB0 + kt, Bs + e0 * 8);
        GL16(gB1 + kt, Bs + e1 * 8);
        __syncthreads();

        bf16x8 af[4], bfr[4];
#pragma unroll
        for (int mi = 0; mi < 4; ++mi)
            af[mi] = *(const bf16x8*)(As + (wm + mi * 16 + r16) * 32 + sw);
#pragma unroll
        for (int ni = 0; ni < 4; ++ni)
            bfr[ni] = *(const bf16x8*)(Bs + (wn + ni * 16 + r16) * 32 + sw);
#pragma unroll
        for (int mi = 0; mi < 4; ++mi)
#pragma unroll
            for (int ni = 0; ni < 4; ++ni)
                acc[mi][ni] = __builtin_amdgcn_mfma_f32_16x16x32_bf16(
                    af[mi], bfr[ni], acc[mi][ni], 0, 0, 0);
    }
}

// ---------------------------------------------------------------------------
// Fused converter: Wqkv -> Wqb/Wkb/Wvs (bf16), Wproj -> WpT (bf16 transposed)
// ---------------------------------------------------------------------------
__global__ __launch_bounds__(256) void conv_all(const float* __restrict__ Wqkv,
                                                const float* __restrict__ Wproj,
                                                unsigned short* __restrict__ Wqb,
                                                unsigned short* __restrict__ Wkb,
                                                unsigned short* __restrict__ Wvs,
                                                unsigned short* __restrict__ WpT) {
    int t = blockIdx.x * 256 + threadIdx.x;
    if (t < 3 * CC * NC) {
        unsigned short v = f2bf(Wqkv[t]);
        int ic = t / NC;           // i*256 + a  (input channel a)
        int col = t - ic * NC;
        if (col < 256)       Wqb[(size_t)ic * CC + col] = v;
        else if (col < 512)  Wkb[(size_t)ic * CC + col - 256] = v;
        else                 Wvs[(size_t)ic * CC + col - 512] = v;
    } else {
        int e = t - 3 * CC * NC;   // < 65536
        int g = e >> 8, c = e & 255;
        WpT[e] = f2bf(Wproj[(size_t)c * CC + g]);   // WpT[g][c] = Wproj[c][g]
    }
}

// ---------------------------------------------------------------------------
// Batched weight GEMM: z<3 -> MtY_i = scale * Wk_i Wq_i^T  (256x256)
//                      z=3 -> PtZ = (1/3) * Wproj^T x Wv   (256x768)
// ---------------------------------------------------------------------------
__global__ __launch_bounds__(256) void wgemm(const unsigned short* __restrict__ Wqb,
                                             const unsigned short* __restrict__ Wkb,
                                             const unsigned short* __restrict__ Wvs,
                                             const unsigned short* __restrict__ WpT,
                                             unsigned short* __restrict__ MtY,
                                             unsigned short* __restrict__ PtZ) {
    const int z = blockIdx.z;
    const unsigned short *A, *Bt;
    unsigned short* C;
    int nout; float mult;
    if (z < 3) {
        if (blockIdx.x >= 2) return;
        A = Wkb + z * CC * CC; Bt = Wqb + z * CC * CC; C = MtY + z * CC * CC;
        nout = CC; mult = 0.0625f;            // C^-0.5
    } else {
        A = WpT; Bt = Wvs; C = PtZ;
        nout = NC; mult = 1.0f / 3.0f;
    }

    __shared__ unsigned short As[128 * 32];
    __shared__ unsigned short Bs[128 * 32];
    f32x4 acc[4][4];
#pragma unroll
    for (int i = 0; i < 4; ++i)
#pragma unroll
        for (int j = 0; j < 4; ++j) acc[i][j] = {0.f, 0.f, 0.f, 0.f};

    gemm_tile<CC>(A, Bt, blockIdx.y * 128, blockIdx.x * 128, As, Bs, acc);

    const int lane = threadIdx.x & 63;
    const int wave = threadIdx.x >> 6;
    const int q = lane >> 4, r16 = lane & 15;
    const int wm = (wave >> 1) * 64, wn = (wave & 1) * 64;
#pragma unroll
    for (int mi = 0; mi < 4; ++mi)
#pragma unroll
        for (int ni = 0; ni < 4; ++ni) {
            int row0 = blockIdx.y * 128 + wm + mi * 16 + q * 4;
            int col = blockIdx.x * 128 + wn + ni * 16 + r16;
#pragma unroll
            for (int r = 0; r < 4; ++r)
                C[(size_t)(row0 + r) * nout + col] = f2bf(acc[mi][ni][r] * mult);
        }
}

// ---------------------------------------------------------------------------
// MEGA kernel, r5 dataflow + skewed weight pipeline.
// Per block of 64 tokens:
//   x staged ONCE into LDS (xbuf, bf16) — r5-proven, keeps FETCH ~x-size.
//   Weights stream through 2 x 4KB LDS stages, loads issued one full stage
//   ahead of use (the compiler's vmcnt(0)-before-barrier drains loads that
//   already had a stage of compute time to fly). One barrier per stage.
//   P1: Y_i = x @ M_i^T -> ybuf; P2: attention in LDS; P3: oacc += z @ P_i.
// LDS: xbuf 70x264 (36960) + ybuf 64x264 (33792) + bstage 2x4096 (8192)
//      = 78944 B -> 2 blocks/CU.  part[768] aliases bstage[1] (dead in P2).
// ---------------------------------------------------------------------------
__global__ __launch_bounds__(256, 2) void mega(const float* __restrict__ xf,
                                               const unsigned short* __restrict__ MtY,
                                               const unsigned short* __restrict__ PtZ,
                                               const float* __restrict__ bias,
                                               float* __restrict__ out) {
    __shared__ __align__(16) unsigned short xbuf[70 * 264];
    __shared__ __align__(16) unsigned short ybuf[64 * 264];
    __shared__ __align__(16) unsigned short bstage[2][2048];   // 2 x 4 KB

    const int tid = threadIdx.x;
    const int lane = tid & 63;
    const int wave = tid >> 6;
    const int q = lane >> 4;
    const int r16 = lane & 15;
    const int t0 = blockIdx.x * 64;

    // Stage one 64-col x 32-k weight slice (4 KB, 1 GL16/thread).
    // Slot e holds col (e>>2), k-chunk (e&3)^((col>>1)&3) (conflict swizzle).
    // P1 weights: MtY rows (i*256 + col), K stride CC.  s = cq*8 + kt.
    auto stage_M = [&](int ii, int s, int b) {
        int cq = s >> 3, kt = s & 7;
        int col = tid >> 2;
        int kc = (tid & 3) ^ ((col >> 1) & 3);
        GL16(MtY + (size_t)(ii * 256 + cq * 64 + col) * CC + kt * 32 + kc * 8,
             bstage[b] + tid * 8);
    };
    // P3 weights: PtZ rows (out ch g), K offset i*256.  s = kt*4 + cq.
    auto stage_P = [&](int ii, int s, int b) {
        int kt = s >> 2, cq = s & 3;
        int col = tid >> 2;
        int kc = (tid & 3) ^ ((col >> 1) & 3);
        GL16(PtZ + (size_t)(cq * 64 + col) * NC + ii * 256 + kt * 32 + kc * 8,
             bstage[b] + tid * 8);
    };

    stage_M(0, 0, 0);   // very first slice — flies while we stage x

    // ---- stage x rows [t0-3, t0+67) fp32 -> bf16 LDS (clamped; masked later)
    for (int it = 0; it < 9; ++it) {
        int e = it * 256 + tid;          // 70 rows * 32 chunks = 2240
        if (e < 2240) {
            int r = e >> 5, c = e & 31;
            int gr = t0 - 3 + r;
            gr = gr < 0 ? 0 : (gr > MTOT - 1 ? MTOT - 1 : gr);
            const float* xp = xf + (size_t)gr * CC + c * 8;
            float4 a = *(const float4*)xp;
            float4 b = *(const float4*)(xp + 4);
            unsigned short p[8];
            p[0] = f2bf(a.x); p[1] = f2bf(a.y); p[2] = f2bf(a.z); p[3] = f2bf(a.w);
            p[4] = f2bf(b.x); p[5] = f2bf(b.y); p[6] = f2bf(b.z); p[7] = f2bf(b.w);
            *(float4*)(xbuf + r * 264 + c * 8) = *(const float4*)p;
        }
    }
    __syncthreads();   // xbuf + first weight stage ready

    // persistent A-fragments: wave's 16 tokens (rows 3+wave*16+r16)
    bf16x8 af[8];
#pragma unroll
    for (int kt = 0; kt < 8; ++kt)
        af[kt] = *(const bf16x8*)(xbuf + (3 + wave * 16 + r16) * 264 + kt * 32 + q * 8);

    f32x4 oacc[16];
#pragma unroll
    for (int j = 0; j < 16; ++j) oacc[j] = {0.f, 0.f, 0.f, 0.f};

    const int fragsw = q ^ ((r16 >> 1) & 3);   // fragment k-chunk swizzle

    for (int i = 0; i < 3; ++i) {
        // ================= Phase 1: Y = x @ M_i^T =================
#pragma unroll
        for (int cq = 0; cq < 4; ++cq) {
            f32x4 yacc[4];
#pragma unroll
            for (int j = 0; j < 4; ++j) yacc[j] = {0.f, 0.f, 0.f, 0.f};
#pragma unroll
            for (int kt = 0; kt < 8; ++kt) {
                const int s = cq * 8 + kt;
                __syncthreads();                 // stage s ready in buf (s&1)
                if (s < 31) stage_M(i, s + 1, (s + 1) & 1);
                else        stage_P(i, 0, 0);    // prefetch phase-3 slice 0
                const unsigned short* bp = bstage[s & 1];
#pragma unroll
                for (int nf = 0; nf < 4; ++nf) {
                    int col = nf * 16 + r16;
                    bf16x8 b = *(const bf16x8*)(bp + (col * 4 + fragsw) * 8);
                    yacc[nf] = __builtin_amdgcn_mfma_f32_16x16x32_bf16(
                        af[kt], b, yacc[nf], 0, 0, 0);
                }
            }
#pragma unroll
            for (int nf = 0; nf < 4; ++nf)
#pragma unroll
                for (int r = 0; r < 4; ++r)
                    ybuf[(wave * 16 + q * 4 + r) * 264 + cq * 64 + nf * 16 + r16] =
                        f2bf(yacc[nf][r]);
        }
        __syncthreads();   // y ready (also drains the stage_P prefetch)

        // ================= Phase 2: attention =================
        {
            const int t = lane, seg = wave;
            const int d = i + 1;
            const int ns = (t0 + t) & (NN - 1);
            const bool vlo = ns >= d;
            const bool vhi = ns + d < NN;
            const unsigned short* yr = ybuf + t * 264 + seg * 64;
            const unsigned short* x0r = xbuf + (3 + t - d) * 264 + seg * 64;
            const unsigned short* x1r = xbuf + (3 + t) * 264 + seg * 64;
            const unsigned short* x2r = xbuf + (3 + t + d) * 264 + seg * 64;
            float* part = (float*)bstage[1];     // dead stage buffer

            float p0 = 0.f, p1 = 0.f, p2 = 0.f;
#pragma unroll
            for (int kk = 0; kk < 8; ++kk) {
                bf16x8 yv = *(const bf16x8*)(yr + kk * 8);
                bf16x8 a0 = *(const bf16x8*)(x0r + kk * 8);
                bf16x8 a1 = *(const bf16x8*)(x1r + kk * 8);
                bf16x8 a2 = *(const bf16x8*)(x2r + kk * 8);
                const unsigned short* yp = (const unsigned short*)&yv;
                const unsigned short* u0 = (const unsigned short*)&a0;
                const unsigned short* u1 = (const unsigned short*)&a1;
                const unsigned short* u2 = (const unsigned short*)&a2;
#pragma unroll
                for (int e = 0; e < 8; ++e) {
                    float yf = bf2f(yp[e]);
                    p0 += yf * bf2f(u0[e]);
                    p1 += yf * bf2f(u1[e]);
                    p2 += yf * bf2f(u2[e]);
                }
            }
            int pb = (seg * 64 + t) * 3;
            part[pb] = p0; part[pb + 1] = p1; part[pb + 2] = p2;
            __syncthreads();   // partials ready

            float l0 = 0.f, l1 = 0.f, l2 = 0.f;
#pragma unroll
            for (int s4 = 0; s4 < 4; ++s4) {
                int b = (s4 * 64 + t) * 3;
                l0 += part[b]; l1 += part[b + 1]; l2 += part[b + 2];
            }
            if (!vlo) l0 = 0.f;        // zero-logit padding (matches reference)
            if (!vhi) l2 = 0.f;
            float mx = fmaxf(l0, fmaxf(l1, l2));
            float e0 = __expf(l0 - mx), e1 = __expf(l1 - mx), e2 = __expf(l2 - mx);
            float inv = 1.0f / (e0 + e1 + e2);
            float w0 = vlo ? e0 * inv : 0.f;
            float w1 = e1 * inv;
            float w2 = vhi ? e2 * inv : 0.f;

            unsigned short* zr = ybuf + t * 264 + seg * 64;
#pragma unroll
            for (int kk = 0; kk < 8; ++kk) {
                bf16x8 a0 = *(const bf16x8*)(x0r + kk * 8);
                bf16x8 a1 = *(const bf16x8*)(x1r + kk * 8);
                bf16x8 a2 = *(const bf16x8*)(x2r + kk * 8);
                const unsigned short* u0 = (const unsigned short*)&a0;
                const unsigned short* u1 = (const unsigned short*)&a1;
                const unsigned short* u2 = (const unsigned short*)&a2;
                unsigned short zs[8];
#pragma unroll
                for (int e = 0; e < 8; ++e)
                    zs[e] = f2bf(w0 * bf2f(u0[e]) + w1 * bf2f(u1[e]) +
                                 w2 * bf2f(u2[e]));
                *(float4*)(zr + kk * 8) = *(const float4*)zs;
            }
        }

        // ================= Phase 3: oacc += z @ P_i =================
#pragma unroll
        for (int kt = 0; kt < 8; ++kt) {
            bf16x8 a;
#pragma unroll
            for (int cq = 0; cq < 4; ++cq) {
                const int s = kt * 4 + cq;
                __syncthreads();                 // stage s ready; z visible at s=0
                if (s < 31)      stage_P(i, s + 1, (s + 1) & 1);
                else if (i < 2)  stage_M(i + 1, 0, 0);   // next dilation
                if (cq == 0)
                    a = *(const bf16x8*)(ybuf + (wave * 16 + r16) * 264 +
                                         kt * 32 + q * 8);
                const unsigned short* bp = bstage[s & 1];
#pragma unroll
                for (int nf = 0; nf < 4; ++nf) {
                    int col = nf * 16 + r16;
                    bf16x8 b = *(const bf16x8*)(bp + (col * 4 + fragsw) * 8);
                    oacc[cq * 4 + nf] = __builtin_amdgcn_mfma_f32_16x16x32_bf16(
                        a, b, oacc[cq * 4 + nf], 0, 0, 0);
                }
            }
        }
    }

    // ================= Epilogue: out = oacc + bias =================
#pragma unroll
    for (int cq = 0; cq < 4; ++cq)
#pragma unroll
        for (int nf = 0; nf < 4; ++nf) {
            int g = cq * 64 + nf * 16 + r16;
            float bc = bias[g];
            f32x4 v = oacc[cq * 4 + nf];
#pragma unroll
            for (int r = 0; r < 4; ++r)
                out[(size_t)(t0 + wave * 16 + q * 4 + r) * CC + g] = v[r] + bc;
        }
}

// ---------------------------------------------------------------------------
extern "C" void kernel_launch(void* const* d_in, const int* in_sizes, int n_in,
                              void* d_out, int out_size, void* d_ws, size_t ws_size,
                              hipStream_t stream) {
    const float* x = (const float*)d_in[0];      // (16, 4096, 256)
    const float* Wqkv = (const float*)d_in[1];   // (3, 256, 768)
    const float* Wproj = (const float*)d_in[2];  // (256, 256)
    const float* bproj = (const float*)d_in[3];  // (256,)
    float* out = (float*)d_out;                  // (16, 4096, 256)

    unsigned short* Wqb = (unsigned short*)d_ws;           // 3*256*256
    unsigned short* Wkb = Wqb + (size_t)3 * CC * CC;
    unsigned short* Wvs = Wkb + (size_t)3 * CC * CC;       // (768,256): [(i,a)][c]
    unsigned short* WpT = Wvs + (size_t)3 * CC * CC;       // (256,256): [g][c]
    unsigned short* MtY = WpT + (size_t)CC * CC;           // (768,256): [(i,b)][a]
    unsigned short* PtZ = MtY + (size_t)NC * CC;           // (256,768): [g][(i,a)]

    conv_all<<<(3 * CC * NC + CC * CC) / 256, 256, 0, stream>>>(
        Wqkv, Wproj, Wqb, Wkb, Wvs, WpT);
    wgemm<<<dim3(6, 2, 4), 256, 0, stream>>>(Wqb, Wkb, Wvs, WpT, MtY, PtZ);
    mega<<<MTOT / 64, 256, 0, stream>>>(x, MtY, PtZ, bproj, out);
}